// Round 8
// baseline (12325.730 us; speedup 1.0000x reference)
//
#include <hip/hip_runtime.h>
#include <math.h>

#define AGENT __HIP_MEMORY_SCOPE_AGENT
typedef unsigned long long u64;

__device__ __forceinline__ float sigf(float x) { return 1.f / (1.f + __expf(-x)); }
__device__ __forceinline__ float tanh_fast(float x) { return 1.f - 2.f / (__expf(2.f * x) + 1.f); }
__device__ __forceinline__ float lrelu(float x) { return x > 0.f ? x : 0.01f * x; }
__device__ __forceinline__ u64 aload64(const u64* p) {
    return __hip_atomic_load(p, __ATOMIC_RELAXED, AGENT);
}
__device__ __forceinline__ void astore64(u64* p, u64 v) {
    __hip_atomic_store(p, v, __ATOMIC_RELAXED, AGENT);
}

// ---------------- generic fp32 GEMM: C[m][n] = sum_k A[m][k]*B[n][k] + bias ----
template <bool LRELU>
__global__ __launch_bounds__(256) void gemm_bias(
    const float* __restrict__ A, const float* __restrict__ B,
    const float* __restrict__ bias1, const float* __restrict__ bias2,
    float* __restrict__ C, int M, int N, int K)
{
    __shared__ float As[16][68];
    __shared__ float Bs[16][68];
    const int tid = threadIdx.x;
    const int m0 = blockIdx.y * 64, n0 = blockIdx.x * 64;
    const int tm = tid >> 4, tn = tid & 15;
    const int lr = tid >> 2;
    const int lk = (tid & 3) * 4;
    float acc[4][4] = {};
    for (int k0 = 0; k0 < K; k0 += 16) {
        float4 av = make_float4(0.f, 0.f, 0.f, 0.f);
        if (m0 + lr < M) av = *(const float4*)&A[(size_t)(m0 + lr) * K + k0 + lk];
        As[lk + 0][lr] = av.x; As[lk + 1][lr] = av.y;
        As[lk + 2][lr] = av.z; As[lk + 3][lr] = av.w;
        float4 bv = make_float4(0.f, 0.f, 0.f, 0.f);
        if (n0 + lr < N) bv = *(const float4*)&B[(size_t)(n0 + lr) * K + k0 + lk];
        Bs[lk + 0][lr] = bv.x; Bs[lk + 1][lr] = bv.y;
        Bs[lk + 2][lr] = bv.z; Bs[lk + 3][lr] = bv.w;
        __syncthreads();
#pragma unroll
        for (int kk = 0; kk < 16; kk++) {
            float a[4], b[4];
#pragma unroll
            for (int i = 0; i < 4; i++) a[i] = As[kk][tm * 4 + i];
#pragma unroll
            for (int j = 0; j < 4; j++) b[j] = Bs[kk][tn * 4 + j];
#pragma unroll
            for (int i = 0; i < 4; i++)
#pragma unroll
                for (int j = 0; j < 4; j++) acc[i][j] += a[i] * b[j];
        }
        __syncthreads();
    }
#pragma unroll
    for (int i = 0; i < 4; i++) {
#pragma unroll
        for (int j = 0; j < 4; j++) {
            int mm = m0 + tm * 4 + i, nn = n0 + tn * 4 + j;
            if (mm < M && nn < N) {
                float v = acc[i][j];
                if (bias1) v += bias1[nn];
                if (bias2) v += bias2[nn];
                if (LRELU) v = lrelu(v);
                C[(size_t)mm * N + nn] = v;
            }
        }
    }
}

// ---------------- merged persistent LSTM1+LSTM2 scan ---------------------------
// 64 WGs. WG w owns h1[8w..8w+8) and h2[4w..4w+4). At iteration t (0..4096):
//   poll h1(t-1) [tag t] and h2(t-2) [tag t]  -- ONE hop serves both layers:
//   GEMV1 input = raw h1(t-1); GEMV2 input = {lrelu(h1(t-1)), h2(t-2)}.
//   compute gates -> h1(t) (if t<4096) and h2(t-1) (if t>=1), publish tagged.
// Tags: h1 slot s stored with tag s+1; h2 slot s stored with tag s+2 (publish
// iter s+1). Pure agent-scope sync (the only mechanism verified to work, R5-R7).
__global__ __launch_bounds__(256) void lstm_pipe(
    const float* __restrict__ gx1, const float* __restrict__ Whh1,
    const float* __restrict__ Wih2, const float* __restrict__ Whh2,
    const float* __restrict__ bih2, const float* __restrict__ bhh2,
    u64* __restrict__ h1pub, u64* __restrict__ h2pub,
    float* __restrict__ h2seq)
{
    const int wg = blockIdx.x, tid = threadIdx.x;
    const int p = tid >> 5, r = tid & 31;
    const int jb1 = wg * 8, jb2 = wg * 4;
    __shared__ float xl[512];      // raw h1(t-1)
    __shared__ float cat[768];     // [0,512)=lrelu(h1(t-1)), [512,768)=h2(t-2)
    __shared__ float part1[8][33];
    __shared__ float part2[16][17];

    // GEMV1 weights: row r (0..31: gate r>>3, elem r&7), K-segment p (64 wide)
    const int grow1 = (r >> 3) * 512 + jb1 + (r & 7);
    float w1[64];
#pragma unroll
    for (int q = 0; q < 64; q++) w1[q] = Whh1[(size_t)grow1 * 512 + p * 64 + q];

    // GEMV2 weights: row2 = r&15 (gate row2>>2, elem row2&3),
    // seg2 = (p<<1)|(r>>4) (0..15), 48 concat-inputs per segment
    const int row2 = r & 15, seg2 = (p << 1) | (r >> 4);
    const int grow2 = (row2 >> 2) * 256 + jb2 + (row2 & 3);
    float w2r[48];
#pragma unroll
    for (int j = 0; j < 48; j++) {
        int idx = seg2 * 48 + j;
        w2r[j] = (idx < 512) ? Wih2[(size_t)grow2 * 512 + idx]
                             : Whh2[(size_t)grow2 * 256 + (idx - 512)];
    }

    float bs = 0.f;  // h2 gate bias, lanes 32..47 of wave 0
    if (tid >= 32 && tid < 48) {
        int l = tid - 32;
        int row = (l >> 2) * 256 + jb2 + (l & 3);
        bs = bih2[row] + bhh2[row];
    }
    float c1 = 0.f, c2 = 0.f;  // cell states: lanes 0..7 (c1), 32..35 (c2)

    for (int t = 0; t <= 4096; ++t) {
        // gx prefetch for h1 step t (issued before the poll for overlap)
        float gxv = 0.f;
        if (t < 4096 && tid < 32)
            gxv = gx1[(size_t)t * 2048 + (tid >> 3) * 512 + jb1 + (tid & 7)];

        // ---- poll (single hop; 2 u64 of h1 + 1 u64 of h2 per thread) ----
        unsigned va = 0, vb = 0, vc = 0;
        if (t >= 1) {
            const u64* p1 = h1pub + (size_t)(t - 1) * 512 + 2 * tid;
            const unsigned want = (unsigned)t;
            if (t >= 2) {
                const u64* p2 = h2pub + (size_t)(t - 2) * 256 + tid;
                u64 a, b, c;
                do {
                    a = aload64(p1); b = aload64(p1 + 1); c = aload64(p2);
                } while (!__all(((unsigned)(a >> 32) == want) &
                                ((unsigned)(b >> 32) == want) &
                                ((unsigned)(c >> 32) == want)));
                va = (unsigned)a; vb = (unsigned)b; vc = (unsigned)c;
            } else {
                u64 a, b;
                do {
                    a = aload64(p1); b = aload64(p1 + 1);
                } while (!__all(((unsigned)(a >> 32) == want) &
                                ((unsigned)(b >> 32) == want)));
                va = (unsigned)a; vb = (unsigned)b;
            }
        }
        {
            float fa = __uint_as_float(va), fb = __uint_as_float(vb);
            xl[2 * tid] = fa;
            xl[2 * tid + 1] = fb;
            cat[2 * tid] = lrelu(fa);
            cat[2 * tid + 1] = lrelu(fb);
            cat[512 + tid] = __uint_as_float(vc);
        }
        __syncthreads();  // B1: inputs ready

        // ---- GEMV1: 64 broadcast MACs ----
        {
            float a0 = 0.f, a1 = 0.f, a2 = 0.f, a3 = 0.f;
            const float* xs = &xl[p * 64];
#pragma unroll
            for (int q = 0; q < 16; q++) {
                a0 += w1[4 * q + 0] * xs[4 * q + 0];
                a1 += w1[4 * q + 1] * xs[4 * q + 1];
                a2 += w1[4 * q + 2] * xs[4 * q + 2];
                a3 += w1[4 * q + 3] * xs[4 * q + 3];
            }
            part1[p][r] = (a0 + a1) + (a2 + a3);
        }
        // ---- GEMV2: 48 MACs over concat segment ----
        {
            float b0 = 0.f, b1 = 0.f, b2 = 0.f, b3 = 0.f;
            const float* cs = &cat[seg2 * 48];
#pragma unroll
            for (int j = 0; j < 12; j++) {
                b0 += w2r[4 * j + 0] * cs[4 * j + 0];
                b1 += w2r[4 * j + 1] * cs[4 * j + 1];
                b2 += w2r[4 * j + 2] * cs[4 * j + 2];
                b3 += w2r[4 * j + 3] * cs[4 * j + 3];
            }
            part2[seg2][row2] = (b0 + b1) + (b2 + b3);
        }
        __syncthreads();  // B2: partials ready

        if (tid < 64) {  // wave 0 does all gate math
            float act = 0.f;
            if (tid < 32) {
                float s = gxv;
#pragma unroll
                for (int pp = 0; pp < 8; pp++) s += part1[pp][tid];
                act = ((tid >> 3) == 2) ? tanh_fast(s) : sigf(s);
            } else if (tid < 48) {
                float s = bs;
#pragma unroll
                for (int ss = 0; ss < 16; ss++) s += part2[ss][tid - 32];
                act = (((tid - 32) >> 2) == 2) ? tanh_fast(s) : sigf(s);
            }
            const int base = tid & 32;
            const int gsz = base ? 4 : 8;
            const int e = tid & 7;
            float vi = __shfl(act, base + e, 64);
            float vf = __shfl(act, base + gsz + e, 64);
            float vg = __shfl(act, base + 2 * gsz + e, 64);
            float vo = __shfl(act, base + 3 * gsz + e, 64);
            if (tid < 8 && t < 4096) {
                c1 = vf * c1 + vi * vg;
                float h = vo * tanh_fast(c1);
                astore64(h1pub + (size_t)t * 512 + jb1 + tid,
                         ((u64)(t + 1) << 32) | (u64)__float_as_uint(h));
            }
            if (tid >= 32 && tid < 36 && t >= 1) {
                c2 = vf * c2 + vi * vg;
                float h = vo * tanh_fast(c2);
                const size_t ofs = (size_t)(t - 1) * 256 + jb2 + (tid - 32);
                astore64(h2pub + ofs,
                         ((u64)(t + 1) << 32) | (u64)__float_as_uint(h));
                h2seq[ofs] = lrelu(h);
            }
        }
    }
}

// ---------------- GCN edge scatter: y[dst] += ew * m[src] ----------------------
__global__ void gcn_scatter(const float* __restrict__ m, const int* __restrict__ ei,
                            const float* __restrict__ ew, float* __restrict__ y,
                            int shift, int nE)
{
    int idx = blockIdx.x * 256 + threadIdx.x;
    int e = idx >> shift;
    if (e >= nE) return;
    int C = 1 << shift;
    int ch = idx & (C - 1);
    int s = ei[e], d = ei[nE + e];
    atomicAdd(&y[(size_t)d * C + ch], ew[e] * m[(size_t)s * C + ch]);
}

// ---------------- BN (training-mode batch stats) -------------------------------
__global__ __launch_bounds__(256) void bn_stats(
    const float* __restrict__ x, const float* __restrict__ gamma,
    const float* __restrict__ beta, float* __restrict__ scale,
    float* __restrict__ shift, int Nn, int C)
{
    int ch = blockIdx.x;
    float s = 0.f, s2 = 0.f;
    for (int n = threadIdx.x; n < Nn; n += 256) {
        float v = x[(size_t)n * C + ch];
        s += v; s2 += v * v;
    }
    __shared__ float rs[256], rq[256];
    rs[threadIdx.x] = s; rq[threadIdx.x] = s2;
    __syncthreads();
    for (int o = 128; o > 0; o >>= 1) {
        if (threadIdx.x < o) {
            rs[threadIdx.x] += rs[threadIdx.x + o];
            rq[threadIdx.x] += rq[threadIdx.x + o];
        }
        __syncthreads();
    }
    if (threadIdx.x == 0) {
        float mean = rs[0] / Nn;
        float var = rq[0] / Nn - mean * mean;
        float inv = rsqrtf(var + 1e-5f);
        float sc = gamma[ch] * inv;
        scale[ch] = sc;
        shift[ch] = beta[ch] - mean * sc;
    }
}

__global__ void bn_apply(const float* __restrict__ x, const float* __restrict__ scale,
                         const float* __restrict__ shift, float* __restrict__ z,
                         int mask, int total)
{
    int idx = blockIdx.x * 256 + threadIdx.x;
    if (idx >= total) return;
    int ch = idx & mask;
    z[idx] = lrelu(x[idx] * scale[ch] + shift[ch]);
}

// ---------------- global_add_pool via batch array ------------------------------
__global__ void pool_kernel(const float* __restrict__ z, const int* __restrict__ batch,
                            float* __restrict__ pooled, int total)
{
    int idx = blockIdx.x * 256 + threadIdx.x;
    if (idx >= total) return;
    int n = idx >> 5, ch = idx & 31;
    atomicAdd(&pooled[(size_t)batch[n] * 32 + ch], z[idx]);
}

// ---------------- final tiny MLP: 32 -> 16 -> 8 -> 2, one thread per graph -----
__global__ void mlp_kernel(const float* __restrict__ pooled,
                           const float* __restrict__ w2, const float* __restrict__ b2,
                           const float* __restrict__ w3, const float* __restrict__ b3,
                           const float* __restrict__ w4, const float* __restrict__ b4,
                           float* __restrict__ out)
{
    int g = blockIdx.x * 256 + threadIdx.x;
    if (g >= 512) return;
    float pbuf[32];
#pragma unroll
    for (int i = 0; i < 32; i++) pbuf[i] = pooled[g * 32 + i];
    float a[16];
#pragma unroll
    for (int j = 0; j < 16; j++) {
        float s = b2[j];
#pragma unroll
        for (int i = 0; i < 32; i++) s += w2[j * 32 + i] * pbuf[i];
        a[j] = lrelu(s);
    }
    float c8[8];
#pragma unroll
    for (int j = 0; j < 8; j++) {
        float s = b3[j];
#pragma unroll
        for (int i = 0; i < 16; i++) s += w3[j * 16 + i] * a[i];
        c8[j] = lrelu(s);
    }
#pragma unroll
    for (int j = 0; j < 2; j++) {
        float s = b4[j];
#pragma unroll
        for (int i = 0; i < 8; i++) s += w4[j * 8 + i] * c8[i];
        out[g * 2 + j] = lrelu(s);
    }
}

extern "C" void kernel_launch(void* const* d_in, const int* in_sizes, int n_in,
                              void* d_out, int out_size, void* d_ws, size_t ws_size,
                              hipStream_t stream)
{
    (void)in_sizes; (void)n_in; (void)out_size; (void)ws_size;
    const float* x      = (const float*)d_in[0];
    const int*   ei     = (const int*)d_in[1];
    const float* ew     = (const float*)d_in[2];
    const int*   batch  = (const int*)d_in[3];
    const float* W_ih1  = (const float*)d_in[4];
    const float* W_hh1  = (const float*)d_in[5];
    const float* b_ih1  = (const float*)d_in[6];
    const float* b_hh1  = (const float*)d_in[7];
    const float* W_ih2  = (const float*)d_in[8];
    const float* W_hh2  = (const float*)d_in[9];
    const float* b_ih2  = (const float*)d_in[10];
    const float* b_hh2  = (const float*)d_in[11];
    const float* fc1_w  = (const float*)d_in[12];
    const float* fc1_b  = (const float*)d_in[13];
    const float* gcn1_w = (const float*)d_in[14];
    const float* bn1_g  = (const float*)d_in[16];
    const float* bn1_b  = (const float*)d_in[17];
    const float* gcn2_w = (const float*)d_in[18];
    const float* bn2_g  = (const float*)d_in[20];
    const float* bn2_b  = (const float*)d_in[21];
    const float* fc2_w  = (const float*)d_in[22];
    const float* fc2_b  = (const float*)d_in[23];
    const float* fc3_w  = (const float*)d_in[24];
    const float* fc3_b  = (const float*)d_in[25];
    const float* fc4_w  = (const float*)d_in[26];
    const float* fc4_b  = (const float*)d_in[27];
    float* out = (float*)d_out;

    // -------- workspace layout (byte offsets) --------
    char* base = (char*)d_ws;
    const size_t MB = 1024 * 1024;
    float* gx1    = (float*)base;                       // 32MB: 4096*2048 f32
    u64*   h1pub  = (u64*)(base + 32 * MB);             // 16MB: 4096*512 u64
    u64*   h2pub  = (u64*)(base + 48 * MB);             //  8MB: 4096*256 u64
    float* h2seq  = (float*)(base + 56 * MB);           //  4MB: 4096*256 f32
    float* scale1 = (float*)(base + 60 * MB);           // 64
    float* shift1 = scale1 + 64;                        // 64
    float* scale2 = shift1 + 64;                        // 32
    float* shift2 = scale2 + 32;                        // 32
    // buffers used only AFTER lstm_pipe — aliased into gx1's space:
    float* h3     = (float*)base;                       // 4096*128
    float* m1     = h3 + (size_t)4096 * 128;            // 4096*64
    float* y1     = m1 + (size_t)4096 * 64;             // 4096*64 (bn in-place)
    float* m2     = y1 + (size_t)4096 * 64;             // 4096*32
    float* y2     = m2 + (size_t)4096 * 32;             // 4096*32 (bn in-place)
    float* pooled = y2 + (size_t)4096 * 32;             // 512*32

    dim3 b256(256);

    // fresh tags every launch (no cross-call state)
    hipMemsetAsync(h1pub, 0, (size_t)24 * MB, stream);  // h1pub + h2pub

    // gx1 = x @ W_ih1^T + (b_ih1 + b_hh1)   [4096,2048]
    gemm_bias<false><<<dim3(2048 / 64, 4096 / 64), b256, 0, stream>>>(
        x, W_ih1, b_ih1, b_hh1, gx1, 4096, 2048, 1280);

    // merged LSTM1+LSTM2 scan, 64 persistent WGs (scheduler-spread)
    lstm_pipe<<<64, b256, 0, stream>>>(gx1, W_hh1, W_ih2, W_hh2, b_ih2, b_hh2,
                                       h1pub, h2pub, h2seq);

    // fc1 + lrelu  [4096,128]
    gemm_bias<true><<<dim3(128 / 64, 4096 / 64), b256, 0, stream>>>(
        h2seq, fc1_w, fc1_b, nullptr, h3, 4096, 128, 256);

    // gcn1 linear [4096,64]  (bias cancels in BN)
    gemm_bias<false><<<dim3(1, 4096 / 64), b256, 0, stream>>>(
        h3, gcn1_w, nullptr, nullptr, m1, 4096, 64, 128);
    hipMemsetAsync(y1, 0, (size_t)4096 * 64 * sizeof(float), stream);
    gcn_scatter<<<(32768 * 64) / 256, b256, 0, stream>>>(m1, ei, ew, y1, 6, 32768);
    bn_stats<<<64, b256, 0, stream>>>(y1, bn1_g, bn1_b, scale1, shift1, 4096, 64);
    bn_apply<<<(4096 * 64) / 256, b256, 0, stream>>>(y1, scale1, shift1, y1, 63, 4096 * 64);

    // gcn2 linear [4096,32]
    gemm_bias<false><<<dim3(1, 4096 / 64), b256, 0, stream>>>(
        y1, gcn2_w, nullptr, nullptr, m2, 4096, 32, 64);
    hipMemsetAsync(y2, 0, (size_t)4096 * 32 * sizeof(float), stream);
    gcn_scatter<<<(32768 * 32) / 256, b256, 0, stream>>>(m2, ei, ew, y2, 5, 32768);
    bn_stats<<<32, b256, 0, stream>>>(y2, bn2_g, bn2_b, scale2, shift2, 4096, 32);
    bn_apply<<<(4096 * 32) / 256, b256, 0, stream>>>(y2, scale2, shift2, y2, 31, 4096 * 32);

    // pool + MLP head
    hipMemsetAsync(pooled, 0, (size_t)512 * 32 * sizeof(float), stream);
    pool_kernel<<<(4096 * 32) / 256, b256, 0, stream>>>(y2, batch, pooled, 4096 * 32);
    mlp_kernel<<<2, b256, 0, stream>>>(pooled, fc2_w, fc2_b, fc3_w, fc3_b,
                                       fc4_w, fc4_b, out);
}

// Round 9
// 9698.507 us; speedup vs baseline: 1.2709x; 1.2709x over previous
//
#include <hip/hip_runtime.h>
#include <math.h>

#define AGENT __HIP_MEMORY_SCOPE_AGENT
typedef unsigned long long u64;

__device__ __forceinline__ float sigf(float x) { return 1.f / (1.f + __expf(-x)); }
__device__ __forceinline__ float tanh_fast(float x) { return 1.f - 2.f / (__expf(2.f * x) + 1.f); }
__device__ __forceinline__ float lrelu(float x) { return x > 0.f ? x : 0.01f * x; }
__device__ __forceinline__ u64 aload64(const u64* p) {
    return __hip_atomic_load(p, __ATOMIC_RELAXED, AGENT);
}
__device__ __forceinline__ void astore64(u64* p, u64 v) {
    __hip_atomic_store(p, v, __ATOMIC_RELAXED, AGENT);
}

// ---------------- generic fp32 GEMM: C[m][n] = sum_k A[m][k]*B[n][k] + bias ----
template <bool LRELU>
__global__ __launch_bounds__(256) void gemm_bias(
    const float* __restrict__ A, const float* __restrict__ B,
    const float* __restrict__ bias1, const float* __restrict__ bias2,
    float* __restrict__ C, int M, int N, int K)
{
    __shared__ float As[16][68];
    __shared__ float Bs[16][68];
    const int tid = threadIdx.x;
    const int m0 = blockIdx.y * 64, n0 = blockIdx.x * 64;
    const int tm = tid >> 4, tn = tid & 15;
    const int lr = tid >> 2;
    const int lk = (tid & 3) * 4;
    float acc[4][4] = {};
    for (int k0 = 0; k0 < K; k0 += 16) {
        float4 av = make_float4(0.f, 0.f, 0.f, 0.f);
        if (m0 + lr < M) av = *(const float4*)&A[(size_t)(m0 + lr) * K + k0 + lk];
        As[lk + 0][lr] = av.x; As[lk + 1][lr] = av.y;
        As[lk + 2][lr] = av.z; As[lk + 3][lr] = av.w;
        float4 bv = make_float4(0.f, 0.f, 0.f, 0.f);
        if (n0 + lr < N) bv = *(const float4*)&B[(size_t)(n0 + lr) * K + k0 + lk];
        Bs[lk + 0][lr] = bv.x; Bs[lk + 1][lr] = bv.y;
        Bs[lk + 2][lr] = bv.z; Bs[lk + 3][lr] = bv.w;
        __syncthreads();
#pragma unroll
        for (int kk = 0; kk < 16; kk++) {
            float a[4], b[4];
#pragma unroll
            for (int i = 0; i < 4; i++) a[i] = As[kk][tm * 4 + i];
#pragma unroll
            for (int j = 0; j < 4; j++) b[j] = Bs[kk][tn * 4 + j];
#pragma unroll
            for (int i = 0; i < 4; i++)
#pragma unroll
                for (int j = 0; j < 4; j++) acc[i][j] += a[i] * b[j];
        }
        __syncthreads();
    }
#pragma unroll
    for (int i = 0; i < 4; i++) {
#pragma unroll
        for (int j = 0; j < 4; j++) {
            int mm = m0 + tm * 4 + i, nn = n0 + tn * 4 + j;
            if (mm < M && nn < N) {
                float v = acc[i][j];
                if (bias1) v += bias1[nn];
                if (bias2) v += bias2[nn];
                if (LRELU) v = lrelu(v);
                C[(size_t)mm * N + nn] = v;
            }
        }
    }
}

// ---------------- persistent pipelined LSTM1+LSTM2 scan ------------------------
// R3 structure (64 LSTM1-WGs + 32 LSTM2-WGs, tagged agent-scope slots), with:
//  * role split per iteration: wave 0 = reduce/act/publish (never polls);
//    waves 1-3 = poll next step's tagged words (tail hidden under poll)
//  * 2-deep pipelined polls (two load batches in flight -> sampling at RT/2)
// Loop shape: [B1] GEMV -> B2 -> {tail || poll} -> B1 ...
__global__ __launch_bounds__(256) void lstm_pipe(
    const float* __restrict__ gx1, const float* __restrict__ Whh1,
    const float* __restrict__ Wih2, const float* __restrict__ Whh2,
    const float* __restrict__ bih2, const float* __restrict__ bhh2,
    u64* __restrict__ h1pub, u64* __restrict__ h2pub,
    float* __restrict__ h2seq)
{
    const int wg = blockIdx.x, tid = threadIdx.x;
    const int wv = tid >> 6;          // wave index 0..3
    const int i192 = tid - 64;        // poller lane id 0..191 (waves 1-3)
    const int p = tid >> 5, r = tid & 31;
    __shared__ float xl[512];
    __shared__ float hl[256];
    __shared__ float part[8][32];

    if (wg < 64) {
        // ---------------- LSTM1: H=512, owns h1[jb..jb+8) ----------------
        const int jb = wg * 8;
        const int grow = (r >> 3) * 512 + jb + (r & 7);
        float w[64];
#pragma unroll
        for (int q = 0; q < 64; q++) w[q] = Whh1[(size_t)grow * 512 + p * 64 + q];
        float c1 = 0.f, gxv = 0.f;

        // poller word assignment: lane i covers words {i, i+192, i+384}
        int we[3]; bool rl[3];
        if (wv > 0) {
#pragma unroll
            for (int j = 0; j < 3; j++) {
                int wd = i192 + 192 * j;
                bool real = (wd < 512) && !(wd >= jb && wd < jb + 8);
                rl[j] = real; we[j] = real ? wd : 0;
            }
        }
        // prologue: xl = h(-1) = 0; prefetch gx(0)
        xl[2 * tid] = 0.f; xl[2 * tid + 1] = 0.f;
        if (tid < 32) gxv = gx1[(size_t)(tid >> 3) * 512 + jb + (tid & 7)];
        __syncthreads();  // B1

        for (int t = 0; t < 4096; ++t) {
            // GEMV over xl = h(t-1)
            float a0 = 0.f, a1 = 0.f, a2 = 0.f, a3 = 0.f;
            const float* xs = &xl[p * 64];
#pragma unroll
            for (int q = 0; q < 16; q++) {
                a0 += w[4 * q + 0] * xs[4 * q + 0];
                a1 += w[4 * q + 1] * xs[4 * q + 1];
                a2 += w[4 * q + 2] * xs[4 * q + 2];
                a3 += w[4 * q + 3] * xs[4 * q + 3];
            }
            part[p][r] = (a0 + a1) + (a2 + a3);
            __syncthreads();  // B2
            if (wv == 0) {
                if (tid < 32) {
                    float s = gxv;
#pragma unroll
                    for (int pp = 0; pp < 8; pp++) s += part[pp][tid];
                    float act = ((tid >> 3) == 2) ? tanh_fast(s) : sigf(s);
                    const int e = tid & 7;
                    float vi = __shfl(act, e, 64);
                    float vf = __shfl(act, e + 8, 64);
                    float vg = __shfl(act, e + 16, 64);
                    float vo = __shfl(act, e + 24, 64);
                    if (tid < 8) {
                        c1 = vf * c1 + vi * vg;
                        float h = vo * tanh_fast(c1);
                        astore64(h1pub + (size_t)t * 512 + jb + tid,
                                 ((u64)(t + 1) << 32) | (u64)__float_as_uint(h));
                        xl[jb + tid] = h;  // own slice for next GEMV
                    }
                    if (t + 1 < 4096)
                        gxv = gx1[(size_t)(t + 1) * 2048 + (tid >> 3) * 512 + jb + (tid & 7)];
                }
            } else if (t + 1 < 4096) {
                // poll h(t) [slot t, tag t+1], 2-deep pipelined
                const u64* bp = h1pub + (size_t)t * 512;
                const unsigned want = (unsigned)(t + 1);
                u64 v0[3], v1[3];
#pragma unroll
                for (int j = 0; j < 3; j++) v0[j] = aload64(bp + we[j]);
#pragma unroll
                for (int j = 0; j < 3; j++) v1[j] = aload64(bp + we[j]);
                for (;;) {
                    bool ok = true;
#pragma unroll
                    for (int j = 0; j < 3; j++)
                        ok &= (!rl[j]) || ((unsigned)(v0[j] >> 32) == want);
                    if (__all(ok)) break;
#pragma unroll
                    for (int j = 0; j < 3; j++) v0[j] = v1[j];
#pragma unroll
                    for (int j = 0; j < 3; j++) v1[j] = aload64(bp + we[j]);
                }
#pragma unroll
                for (int j = 0; j < 3; j++)
                    if (rl[j]) xl[we[j]] = __uint_as_float((unsigned)v0[j]);
            }
            __syncthreads();  // B1 for next iter
        }
    } else {
        // ---------------- LSTM2: H=256, owns h2[jb2..jb2+8) -------------------
        const int k = wg - 64, jb2 = k * 8;
        const int grow = (r >> 3) * 256 + jb2 + (r & 7);
        float wi[64], wh[32];
#pragma unroll
        for (int q = 0; q < 64; q++) wi[q] = Wih2[(size_t)grow * 512 + p * 64 + q];
#pragma unroll
        for (int q = 0; q < 32; q++) wh[q] = Whh2[(size_t)grow * 256 + p * 32 + q];
        float bs = 0.f;
        if (tid < 32) {
            int row = (tid >> 3) * 256 + jb2 + (tid & 7);
            bs = bih2[row] + bhh2[row];
        }
        float c2 = 0.f;

        // poller word assignment: lane i covers {i, i+192, i+384, i+576};
        // words 0..511 = h1 (always foreign), 512..767 = h2 (skip own)
        int we[4]; bool rl[4], ish1[4];
        if (wv > 0) {
#pragma unroll
            for (int j = 0; j < 4; j++) {
                int wd = i192 + 192 * j;
                bool h1w = (wd < 512);
                bool real = h1w || !((wd - 512) >= jb2 && (wd - 512) < jb2 + 8);
                ish1[j] = h1w; rl[j] = real; we[j] = wd;
            }
        }
        // prologue: hl = h2(-1) = 0; xl = lrelu(h1(0)) via poll of slot 0
        hl[tid] = 0.f;
        if (wv > 0) {
            const u64* bp = h1pub;  // slot 0
            const unsigned want = 1u;
            u64 v0[4], v1[4];
#pragma unroll
            for (int j = 0; j < 4; j++) v0[j] = aload64(bp + (ish1[j] ? we[j] : 0));
#pragma unroll
            for (int j = 0; j < 4; j++) v1[j] = aload64(bp + (ish1[j] ? we[j] : 0));
            for (;;) {
                bool ok = true;
#pragma unroll
                for (int j = 0; j < 4; j++)
                    ok &= (!ish1[j]) || ((unsigned)(v0[j] >> 32) == want);
                if (__all(ok)) break;
#pragma unroll
                for (int j = 0; j < 4; j++) v0[j] = v1[j];
#pragma unroll
                for (int j = 0; j < 4; j++) v1[j] = aload64(bp + (ish1[j] ? we[j] : 0));
            }
#pragma unroll
            for (int j = 0; j < 4; j++)
                if (ish1[j]) xl[we[j]] = lrelu(__uint_as_float((unsigned)v0[j]));
        }
        __syncthreads();  // B1

        for (int t = 0; t < 4096; ++t) {
            // GEMV2 over xl = lrelu(h1(t)), hl = h2(t-1)
            float a0 = 0.f, a1 = 0.f, a2 = 0.f, a3 = 0.f;
            const float* xs = &xl[p * 64];
            const float* hs = &hl[p * 32];
#pragma unroll
            for (int q = 0; q < 16; q++) {
                a0 += wi[4 * q + 0] * xs[4 * q + 0];
                a1 += wi[4 * q + 1] * xs[4 * q + 1];
                a2 += wi[4 * q + 2] * xs[4 * q + 2];
                a3 += wi[4 * q + 3] * xs[4 * q + 3];
            }
#pragma unroll
            for (int q = 0; q < 8; q++) {
                a0 += wh[4 * q + 0] * hs[4 * q + 0];
                a1 += wh[4 * q + 1] * hs[4 * q + 1];
                a2 += wh[4 * q + 2] * hs[4 * q + 2];
                a3 += wh[4 * q + 3] * hs[4 * q + 3];
            }
            part[p][r] = (a0 + a1) + (a2 + a3);
            __syncthreads();  // B2
            if (wv == 0) {
                if (tid < 32) {
                    float s = bs;
#pragma unroll
                    for (int pp = 0; pp < 8; pp++) s += part[pp][tid];
                    float act = ((tid >> 3) == 2) ? tanh_fast(s) : sigf(s);
                    const int e = tid & 7;
                    float vi = __shfl(act, e, 64);
                    float vf = __shfl(act, e + 8, 64);
                    float vg = __shfl(act, e + 16, 64);
                    float vo = __shfl(act, e + 24, 64);
                    if (tid < 8) {
                        c2 = vf * c2 + vi * vg;
                        float h = vo * tanh_fast(c2);
                        const size_t ofs = (size_t)t * 256 + jb2 + tid;
                        astore64(h2pub + ofs,
                                 ((u64)(t + 1) << 32) | (u64)__float_as_uint(h));
                        h2seq[ofs] = lrelu(h);
                        hl[jb2 + tid] = h;  // own slice for next GEMV
                    }
                }
            } else if (t + 1 < 4096) {
                // poll h1(t+1) [slot t+1, tag t+2] and h2(t) foreign [slot t, tag t+1]
                const u64* bp1 = h1pub + (size_t)(t + 1) * 512;
                const u64* bp2 = h2pub + (size_t)t * 256;
                const unsigned w1 = (unsigned)(t + 2), w2 = (unsigned)(t + 1);
                const u64* ad[4];
#pragma unroll
                for (int j = 0; j < 4; j++)
                    ad[j] = ish1[j] ? (bp1 + we[j])
                                    : (bp2 + (rl[j] ? (we[j] - 512) : 0));
                u64 v0[4], v1[4];
#pragma unroll
                for (int j = 0; j < 4; j++) v0[j] = aload64(ad[j]);
#pragma unroll
                for (int j = 0; j < 4; j++) v1[j] = aload64(ad[j]);
                for (;;) {
                    bool ok = true;
#pragma unroll
                    for (int j = 0; j < 4; j++) {
                        unsigned want = ish1[j] ? w1 : w2;
                        ok &= (!rl[j]) || ((unsigned)(v0[j] >> 32) == want);
                    }
                    if (__all(ok)) break;
#pragma unroll
                    for (int j = 0; j < 4; j++) v0[j] = v1[j];
#pragma unroll
                    for (int j = 0; j < 4; j++) v1[j] = aload64(ad[j]);
                }
#pragma unroll
                for (int j = 0; j < 4; j++) {
                    if (!rl[j]) continue;
                    float f = __uint_as_float((unsigned)v0[j]);
                    if (ish1[j]) xl[we[j]] = lrelu(f);
                    else hl[we[j] - 512] = f;
                }
            }
            __syncthreads();  // B1 for next iter
        }
    }
}

// ---------------- GCN edge scatter: y[dst] += ew * m[src] ----------------------
__global__ void gcn_scatter(const float* __restrict__ m, const int* __restrict__ ei,
                            const float* __restrict__ ew, float* __restrict__ y,
                            int shift, int nE)
{
    int idx = blockIdx.x * 256 + threadIdx.x;
    int e = idx >> shift;
    if (e >= nE) return;
    int C = 1 << shift;
    int ch = idx & (C - 1);
    int s = ei[e], d = ei[nE + e];
    atomicAdd(&y[(size_t)d * C + ch], ew[e] * m[(size_t)s * C + ch]);
}

// ---------------- BN (training-mode batch stats) -------------------------------
__global__ __launch_bounds__(256) void bn_stats(
    const float* __restrict__ x, const float* __restrict__ gamma,
    const float* __restrict__ beta, float* __restrict__ scale,
    float* __restrict__ shift, int Nn, int C)
{
    int ch = blockIdx.x;
    float s = 0.f, s2 = 0.f;
    for (int n = threadIdx.x; n < Nn; n += 256) {
        float v = x[(size_t)n * C + ch];
        s += v; s2 += v * v;
    }
    __shared__ float rs[256], rq[256];
    rs[threadIdx.x] = s; rq[threadIdx.x] = s2;
    __syncthreads();
    for (int o = 128; o > 0; o >>= 1) {
        if (threadIdx.x < o) {
            rs[threadIdx.x] += rs[threadIdx.x + o];
            rq[threadIdx.x] += rq[threadIdx.x + o];
        }
        __syncthreads();
    }
    if (threadIdx.x == 0) {
        float mean = rs[0] / Nn;
        float var = rq[0] / Nn - mean * mean;
        float inv = rsqrtf(var + 1e-5f);
        float sc = gamma[ch] * inv;
        scale[ch] = sc;
        shift[ch] = beta[ch] - mean * sc;
    }
}

__global__ void bn_apply(const float* __restrict__ x, const float* __restrict__ scale,
                         const float* __restrict__ shift, float* __restrict__ z,
                         int mask, int total)
{
    int idx = blockIdx.x * 256 + threadIdx.x;
    if (idx >= total) return;
    int ch = idx & mask;
    z[idx] = lrelu(x[idx] * scale[ch] + shift[ch]);
}

// ---------------- global_add_pool via batch array ------------------------------
__global__ void pool_kernel(const float* __restrict__ z, const int* __restrict__ batch,
                            float* __restrict__ pooled, int total)
{
    int idx = blockIdx.x * 256 + threadIdx.x;
    if (idx >= total) return;
    int n = idx >> 5, ch = idx & 31;
    atomicAdd(&pooled[(size_t)batch[n] * 32 + ch], z[idx]);
}

// ---------------- final tiny MLP: 32 -> 16 -> 8 -> 2, one thread per graph -----
__global__ void mlp_kernel(const float* __restrict__ pooled,
                           const float* __restrict__ w2, const float* __restrict__ b2,
                           const float* __restrict__ w3, const float* __restrict__ b3,
                           const float* __restrict__ w4, const float* __restrict__ b4,
                           float* __restrict__ out)
{
    int g = blockIdx.x * 256 + threadIdx.x;
    if (g >= 512) return;
    float pbuf[32];
#pragma unroll
    for (int i = 0; i < 32; i++) pbuf[i] = pooled[g * 32 + i];
    float a[16];
#pragma unroll
    for (int j = 0; j < 16; j++) {
        float s = b2[j];
#pragma unroll
        for (int i = 0; i < 32; i++) s += w2[j * 32 + i] * pbuf[i];
        a[j] = lrelu(s);
    }
    float c8[8];
#pragma unroll
    for (int j = 0; j < 8; j++) {
        float s = b3[j];
#pragma unroll
        for (int i = 0; i < 16; i++) s += w3[j * 16 + i] * a[i];
        c8[j] = lrelu(s);
    }
#pragma unroll
    for (int j = 0; j < 2; j++) {
        float s = b4[j];
#pragma unroll
        for (int i = 0; i < 8; i++) s += w4[j * 8 + i] * c8[i];
        out[g * 2 + j] = lrelu(s);
    }
}

extern "C" void kernel_launch(void* const* d_in, const int* in_sizes, int n_in,
                              void* d_out, int out_size, void* d_ws, size_t ws_size,
                              hipStream_t stream)
{
    (void)in_sizes; (void)n_in; (void)out_size; (void)ws_size;
    const float* x      = (const float*)d_in[0];
    const int*   ei     = (const int*)d_in[1];
    const float* ew     = (const float*)d_in[2];
    const int*   batch  = (const int*)d_in[3];
    const float* W_ih1  = (const float*)d_in[4];
    const float* W_hh1  = (const float*)d_in[5];
    const float* b_ih1  = (const float*)d_in[6];
    const float* b_hh1  = (const float*)d_in[7];
    const float* W_ih2  = (const float*)d_in[8];
    const float* W_hh2  = (const float*)d_in[9];
    const float* b_ih2  = (const float*)d_in[10];
    const float* b_hh2  = (const float*)d_in[11];
    const float* fc1_w  = (const float*)d_in[12];
    const float* fc1_b  = (const float*)d_in[13];
    const float* gcn1_w = (const float*)d_in[14];
    const float* bn1_g  = (const float*)d_in[16];
    const float* bn1_b  = (const float*)d_in[17];
    const float* gcn2_w = (const float*)d_in[18];
    const float* bn2_g  = (const float*)d_in[20];
    const float* bn2_b  = (const float*)d_in[21];
    const float* fc2_w  = (const float*)d_in[22];
    const float* fc2_b  = (const float*)d_in[23];
    const float* fc3_w  = (const float*)d_in[24];
    const float* fc3_b  = (const float*)d_in[25];
    const float* fc4_w  = (const float*)d_in[26];
    const float* fc4_b  = (const float*)d_in[27];
    float* out = (float*)d_out;

    // -------- workspace layout (byte offsets) --------
    char* base = (char*)d_ws;
    const size_t MB = 1024 * 1024;
    float* gx1    = (float*)base;                       // 32MB: 4096*2048 f32
    u64*   h1pub  = (u64*)(base + 32 * MB);             // 16MB: 4096*512 u64
    u64*   h2pub  = (u64*)(base + 48 * MB);             //  8MB: 4096*256 u64
    float* h2seq  = (float*)(base + 56 * MB);           //  4MB: 4096*256 f32
    float* scale1 = (float*)(base + 60 * MB);           // 64
    float* shift1 = scale1 + 64;                        // 64
    float* scale2 = shift1 + 64;                        // 32
    float* shift2 = scale2 + 32;                        // 32
    // buffers used only AFTER lstm_pipe — aliased into gx1's space:
    float* h3     = (float*)base;                       // 4096*128
    float* m1     = h3 + (size_t)4096 * 128;            // 4096*64
    float* y1     = m1 + (size_t)4096 * 64;             // 4096*64 (bn in-place)
    float* m2     = y1 + (size_t)4096 * 64;             // 4096*32
    float* y2     = m2 + (size_t)4096 * 32;             // 4096*32 (bn in-place)
    float* pooled = y2 + (size_t)4096 * 32;             // 512*32

    dim3 b256(256);

    // fresh tags every launch (no cross-call state)
    hipMemsetAsync(h1pub, 0, (size_t)24 * MB, stream);  // h1pub + h2pub

    // gx1 = x @ W_ih1^T + (b_ih1 + b_hh1)   [4096,2048]
    gemm_bias<false><<<dim3(2048 / 64, 4096 / 64), b256, 0, stream>>>(
        x, W_ih1, b_ih1, b_hh1, gx1, 4096, 2048, 1280);

    // both LSTM scans, pipelined (persistent, 96 WGs)
    lstm_pipe<<<96, b256, 0, stream>>>(gx1, W_hh1, W_ih2, W_hh2, b_ih2, b_hh2,
                                       h1pub, h2pub, h2seq);

    // fc1 + lrelu  [4096,128]
    gemm_bias<true><<<dim3(128 / 64, 4096 / 64), b256, 0, stream>>>(
        h2seq, fc1_w, fc1_b, nullptr, h3, 4096, 128, 256);

    // gcn1 linear [4096,64]  (bias cancels in BN)
    gemm_bias<false><<<dim3(1, 4096 / 64), b256, 0, stream>>>(
        h3, gcn1_w, nullptr, nullptr, m1, 4096, 64, 128);
    hipMemsetAsync(y1, 0, (size_t)4096 * 64 * sizeof(float), stream);
    gcn_scatter<<<(32768 * 64) / 256, b256, 0, stream>>>(m1, ei, ew, y1, 6, 32768);
    bn_stats<<<64, b256, 0, stream>>>(y1, bn1_g, bn1_b, scale1, shift1, 4096, 64);
    bn_apply<<<(4096 * 64) / 256, b256, 0, stream>>>(y1, scale1, shift1, y1, 63, 4096 * 64);

    // gcn2 linear [4096,32]
    gemm_bias<false><<<dim3(1, 4096 / 64), b256, 0, stream>>>(
        y1, gcn2_w, nullptr, nullptr, m2, 4096, 32, 64);
    hipMemsetAsync(y2, 0, (size_t)4096 * 32 * sizeof(float), stream);
    gcn_scatter<<<(32768 * 32) / 256, b256, 0, stream>>>(m2, ei, ew, y2, 5, 32768);
    bn_stats<<<32, b256, 0, stream>>>(y2, bn2_g, bn2_b, scale2, shift2, 4096, 32);
    bn_apply<<<(4096 * 32) / 256, b256, 0, stream>>>(y2, scale2, shift2, y2, 31, 4096 * 32);

    // pool + MLP head
    hipMemsetAsync(pooled, 0, (size_t)512 * 32 * sizeof(float), stream);
    pool_kernel<<<(4096 * 32) / 256, b256, 0, stream>>>(y2, batch, pooled, 4096 * 32);
    mlp_kernel<<<2, b256, 0, stream>>>(pooled, fc2_w, fc2_b, fc3_w, fc3_b,
                                       fc4_w, fc4_b, out);
}

// Round 10
// 7557.536 us; speedup vs baseline: 1.6309x; 1.2833x over previous
//
#include <hip/hip_runtime.h>
#include <math.h>

#define AGENT __HIP_MEMORY_SCOPE_AGENT
typedef unsigned long long u64;
typedef unsigned int uv4 __attribute__((ext_vector_type(4)));

__device__ __forceinline__ float sigf(float x) { return 1.f / (1.f + __expf(-x)); }
__device__ __forceinline__ float tanh_fast(float x) { return 1.f - 2.f / (__expf(2.f * x) + 1.f); }
__device__ __forceinline__ float lrelu(float x) { return x > 0.f ? x : 0.01f * x; }
__device__ __forceinline__ u64 aload64(const u64* p) {
    return __hip_atomic_load(p, __ATOMIC_RELAXED, AGENT);
}
__device__ __forceinline__ void astore64(u64* p, u64 v) {
    __hip_atomic_store(p, v, __ATOMIC_RELAXED, AGENT);
}

// ---------------- generic fp32 GEMM: C[m][n] = sum_k A[m][k]*B[n][k] + bias ----
template <bool LRELU>
__global__ __launch_bounds__(256) void gemm_bias(
    const float* __restrict__ A, const float* __restrict__ B,
    const float* __restrict__ bias1, const float* __restrict__ bias2,
    float* __restrict__ C, int M, int N, int K)
{
    __shared__ float As[16][68];
    __shared__ float Bs[16][68];
    const int tid = threadIdx.x;
    const int m0 = blockIdx.y * 64, n0 = blockIdx.x * 64;
    const int tm = tid >> 4, tn = tid & 15;
    const int lr = tid >> 2;
    const int lk = (tid & 3) * 4;
    float acc[4][4] = {};
    for (int k0 = 0; k0 < K; k0 += 16) {
        float4 av = make_float4(0.f, 0.f, 0.f, 0.f);
        if (m0 + lr < M) av = *(const float4*)&A[(size_t)(m0 + lr) * K + k0 + lk];
        As[lk + 0][lr] = av.x; As[lk + 1][lr] = av.y;
        As[lk + 2][lr] = av.z; As[lk + 3][lr] = av.w;
        float4 bv = make_float4(0.f, 0.f, 0.f, 0.f);
        if (n0 + lr < N) bv = *(const float4*)&B[(size_t)(n0 + lr) * K + k0 + lk];
        Bs[lk + 0][lr] = bv.x; Bs[lk + 1][lr] = bv.y;
        Bs[lk + 2][lr] = bv.z; Bs[lk + 3][lr] = bv.w;
        __syncthreads();
#pragma unroll
        for (int kk = 0; kk < 16; kk++) {
            float a[4], b[4];
#pragma unroll
            for (int i = 0; i < 4; i++) a[i] = As[kk][tm * 4 + i];
#pragma unroll
            for (int j = 0; j < 4; j++) b[j] = Bs[kk][tn * 4 + j];
#pragma unroll
            for (int i = 0; i < 4; i++)
#pragma unroll
                for (int j = 0; j < 4; j++) acc[i][j] += a[i] * b[j];
        }
        __syncthreads();
    }
#pragma unroll
    for (int i = 0; i < 4; i++) {
#pragma unroll
        for (int j = 0; j < 4; j++) {
            int mm = m0 + tm * 4 + i, nn = n0 + tn * 4 + j;
            if (mm < M && nn < N) {
                float v = acc[i][j];
                if (bias1) v += bias1[nn];
                if (bias2) v += bias2[nn];
                if (LRELU) v = lrelu(v);
                C[(size_t)mm * N + nn] = v;
            }
        }
    }
}

// ---------------- persistent pipelined LSTM1+LSTM2 scan ------------------------
// R3 structure exactly (64 LSTM1-WGs + 32 LSTM2-WGs; tagged agent slots;
// poll -> B1 -> GEMV -> B2 -> tail; tail overlaps other waves' next poll).
// Deltas vs R3:
//  * pollers SKIP the WG's own words; the tail writes its own h slice into LDS
//    (no wait on own store's L3 round trip)
//  * fast poll via global_load_dwordx4 sc1 (agent-visibility bit = L2 bypass;
//    sc0 was the wrong bit in R5-R7) fetching both tagged words in one op,
//    with per-lane adaptive fallback (1024 spins) to proven aload64 polls.
__global__ __launch_bounds__(256) void lstm_pipe(
    const float* __restrict__ gx1, const float* __restrict__ Whh1,
    const float* __restrict__ Wih2, const float* __restrict__ Whh2,
    const float* __restrict__ bih2, const float* __restrict__ bhh2,
    u64* __restrict__ h1pub, u64* __restrict__ h2pub,
    float* __restrict__ h2seq)
{
    const int wg = blockIdx.x, tid = threadIdx.x;
    const int r = tid & 31, p = tid >> 5;
    __shared__ float xl[512];
    __shared__ float hl[256];
    __shared__ float part[8][32];

    if (wg < 64) {
        // ---------------- LSTM1: H=512, owns h1[jb..jb+8) ----------------
        const int jb = wg * 8;
        const int grow = (r >> 3) * 512 + jb + (r & 7);
        float w[64];
#pragma unroll
        for (int q = 0; q < 64; q++) w[q] = Whh1[(size_t)grow * 512 + p * 64 + q];
        float c1 = 0.f;  // cell state, lanes 0..7 of wave 0
        const bool ownpair = (2 * tid >= jb) && (2 * tid < jb + 8);
        bool fastp = true;

        for (int t = 0; t < 4096; ++t) {
            // gx prefetch for this step (issued before the poll; overlaps it)
            float gxv = 0.f;
            if (tid < 32) gxv = gx1[(size_t)t * 2048 + (tid >> 3) * 512 + jb + (tid & 7)];
            if (t == 0) {
                xl[2 * tid] = 0.f; xl[2 * tid + 1] = 0.f;
            } else if (!ownpair) {
                const u64* pa = h1pub + (size_t)(t - 1) * 512 + 2 * tid;
                const unsigned want = (unsigned)t;
                unsigned lo0 = 0, lo1 = 0; bool got = false;
                if (fastp) {
                    int spins = 0;
                    for (;;) {
                        uv4 v;
                        asm volatile("global_load_dwordx4 %0, %1, off sc1\n\t"
                                     "s_waitcnt vmcnt(0)"
                                     : "=&v"(v) : "v"(pa) : "memory");
                        if (v.y == want && v.w == want) {
                            lo0 = v.x; lo1 = v.z; got = true; break;
                        }
                        if (++spins > 1024) { fastp = false; break; }
                    }
                }
                if (!got) {
                    u64 a, b;
                    do { a = aload64(pa); } while ((unsigned)(a >> 32) != want);
                    do { b = aload64(pa + 1); } while ((unsigned)(b >> 32) != want);
                    lo0 = (unsigned)a; lo1 = (unsigned)b;
                }
                xl[2 * tid] = __uint_as_float(lo0);
                xl[2 * tid + 1] = __uint_as_float(lo1);
            }
            __syncthreads();  // B1: xl ready
            float a0 = 0.f, a1 = 0.f, a2 = 0.f, a3 = 0.f;
            const float* xs = &xl[p * 64];
#pragma unroll
            for (int q = 0; q < 16; q++) {
                a0 += w[4 * q + 0] * xs[4 * q + 0];
                a1 += w[4 * q + 1] * xs[4 * q + 1];
                a2 += w[4 * q + 2] * xs[4 * q + 2];
                a3 += w[4 * q + 3] * xs[4 * q + 3];
            }
            part[p][r] = (a0 + a1) + (a2 + a3);
            __syncthreads();  // B2: partials ready
            if (tid < 32) {
                float s = gxv;
#pragma unroll
                for (int pp = 0; pp < 8; pp++) s += part[pp][tid];
                float act = ((tid >> 3) == 2) ? tanh_fast(s) : sigf(s);
                const int e = tid & 7;
                float vi = __shfl(act, e, 64);
                float vf = __shfl(act, e + 8, 64);
                float vg = __shfl(act, e + 16, 64);
                float vo = __shfl(act, e + 24, 64);
                if (tid < 8) {
                    c1 = vf * c1 + vi * vg;
                    float h = vo * tanh_fast(c1);
                    astore64(h1pub + (size_t)t * 512 + jb + tid,
                             ((u64)(t + 1) << 32) | (u64)__float_as_uint(h));
                    xl[jb + tid] = h;  // own slice for next step (pollers skip it)
                }
            }
        }
    } else {
        // ---------------- LSTM2: H=256, pipelined 1 step behind ----------------
        const int k = wg - 64, jb2 = k * 8;
        const int grow = (r >> 3) * 256 + jb2 + (r & 7);
        float wi[64], wh[32];
#pragma unroll
        for (int q = 0; q < 64; q++) wi[q] = Wih2[(size_t)grow * 512 + p * 64 + q];
#pragma unroll
        for (int q = 0; q < 32; q++) wh[q] = Whh2[(size_t)grow * 256 + p * 32 + q];
        float bs = 0.f;
        if (tid < 32) {
            int row = (tid >> 3) * 256 + jb2 + (tid & 7);
            bs = bih2[row] + bhh2[row];
        }
        float c2 = 0.f;
        const bool ownh2 = (tid >= jb2) && (tid < jb2 + 8);
        bool fastp = true;

        for (int t = 0; t < 4096; ++t) {
            {
                // poll h1(t) [tag t+1]: pair {2tid, 2tid+1} (always foreign)
                const u64* pa = h1pub + (size_t)t * 512 + 2 * tid;
                const unsigned want1 = (unsigned)(t + 1);
                unsigned lo0 = 0, lo1 = 0; bool got = false;
                if (fastp) {
                    int spins = 0;
                    for (;;) {
                        uv4 v;
                        asm volatile("global_load_dwordx4 %0, %1, off sc1\n\t"
                                     "s_waitcnt vmcnt(0)"
                                     : "=&v"(v) : "v"(pa) : "memory");
                        if (v.y == want1 && v.w == want1) {
                            lo0 = v.x; lo1 = v.z; got = true; break;
                        }
                        if (++spins > 1024) { fastp = false; break; }
                    }
                }
                if (!got) {
                    u64 a, b;
                    do { a = aload64(pa); } while ((unsigned)(a >> 32) != want1);
                    do { b = aload64(pa + 1); } while ((unsigned)(b >> 32) != want1);
                    lo0 = (unsigned)a; lo1 = (unsigned)b;
                }
                xl[2 * tid] = lrelu(__uint_as_float(lo0));
                xl[2 * tid + 1] = lrelu(__uint_as_float(lo1));
                // poll h2(t-1) [tag t]: word tid, skip own (tail fills it)
                if (t == 0) {
                    hl[tid] = 0.f;
                } else if (!ownh2) {
                    const u64* pb = h2pub + (size_t)(t - 1) * 256 + tid;
                    const unsigned want2 = (unsigned)t;
                    u64 c;
                    do { c = aload64(pb); } while ((unsigned)(c >> 32) != want2);
                    hl[tid] = __uint_as_float((unsigned)c);
                }
            }
            __syncthreads();  // B1
            float a0 = 0.f, a1 = 0.f, a2 = 0.f, a3 = 0.f;
            const float* xs = &xl[p * 64];
            const float* hs = &hl[p * 32];
#pragma unroll
            for (int q = 0; q < 16; q++) {
                a0 += wi[4 * q + 0] * xs[4 * q + 0];
                a1 += wi[4 * q + 1] * xs[4 * q + 1];
                a2 += wi[4 * q + 2] * xs[4 * q + 2];
                a3 += wi[4 * q + 3] * xs[4 * q + 3];
            }
#pragma unroll
            for (int q = 0; q < 8; q++) {
                a0 += wh[4 * q + 0] * hs[4 * q + 0];
                a1 += wh[4 * q + 1] * hs[4 * q + 1];
                a2 += wh[4 * q + 2] * hs[4 * q + 2];
                a3 += wh[4 * q + 3] * hs[4 * q + 3];
            }
            part[p][r] = (a0 + a1) + (a2 + a3);
            __syncthreads();  // B2
            if (tid < 32) {
                float s = bs;
#pragma unroll
                for (int pp = 0; pp < 8; pp++) s += part[pp][tid];
                float act = ((tid >> 3) == 2) ? tanh_fast(s) : sigf(s);
                const int e = tid & 7;
                float vi = __shfl(act, e, 64);
                float vf = __shfl(act, e + 8, 64);
                float vg = __shfl(act, e + 16, 64);
                float vo = __shfl(act, e + 24, 64);
                if (tid < 8) {
                    c2 = vf * c2 + vi * vg;
                    float h = vo * tanh_fast(c2);
                    const size_t ofs = (size_t)t * 256 + jb2 + tid;
                    astore64(h2pub + ofs,
                             ((u64)(t + 1) << 32) | (u64)__float_as_uint(h));
                    h2seq[ofs] = lrelu(h);
                    hl[jb2 + tid] = h;  // own slice for next step
                }
            }
        }
    }
}

// ---------------- GCN edge scatter: y[dst] += ew * m[src] ----------------------
__global__ void gcn_scatter(const float* __restrict__ m, const int* __restrict__ ei,
                            const float* __restrict__ ew, float* __restrict__ y,
                            int shift, int nE)
{
    int idx = blockIdx.x * 256 + threadIdx.x;
    int e = idx >> shift;
    if (e >= nE) return;
    int C = 1 << shift;
    int ch = idx & (C - 1);
    int s = ei[e], d = ei[nE + e];
    atomicAdd(&y[(size_t)d * C + ch], ew[e] * m[(size_t)s * C + ch]);
}

// ---------------- BN (training-mode batch stats) -------------------------------
__global__ __launch_bounds__(256) void bn_stats(
    const float* __restrict__ x, const float* __restrict__ gamma,
    const float* __restrict__ beta, float* __restrict__ scale,
    float* __restrict__ shift, int Nn, int C)
{
    int ch = blockIdx.x;
    float s = 0.f, s2 = 0.f;
    for (int n = threadIdx.x; n < Nn; n += 256) {
        float v = x[(size_t)n * C + ch];
        s += v; s2 += v * v;
    }
    __shared__ float rs[256], rq[256];
    rs[threadIdx.x] = s; rq[threadIdx.x] = s2;
    __syncthreads();
    for (int o = 128; o > 0; o >>= 1) {
        if (threadIdx.x < o) {
            rs[threadIdx.x] += rs[threadIdx.x + o];
            rq[threadIdx.x] += rq[threadIdx.x + o];
        }
        __syncthreads();
    }
    if (threadIdx.x == 0) {
        float mean = rs[0] / Nn;
        float var = rq[0] / Nn - mean * mean;
        float inv = rsqrtf(var + 1e-5f);
        float sc = gamma[ch] * inv;
        scale[ch] = sc;
        shift[ch] = beta[ch] - mean * sc;
    }
}

__global__ void bn_apply(const float* __restrict__ x, const float* __restrict__ scale,
                         const float* __restrict__ shift, float* __restrict__ z,
                         int mask, int total)
{
    int idx = blockIdx.x * 256 + threadIdx.x;
    if (idx >= total) return;
    int ch = idx & mask;
    z[idx] = lrelu(x[idx] * scale[ch] + shift[ch]);
}

// ---------------- global_add_pool via batch array ------------------------------
__global__ void pool_kernel(const float* __restrict__ z, const int* __restrict__ batch,
                            float* __restrict__ pooled, int total)
{
    int idx = blockIdx.x * 256 + threadIdx.x;
    if (idx >= total) return;
    int n = idx >> 5, ch = idx & 31;
    atomicAdd(&pooled[(size_t)batch[n] * 32 + ch], z[idx]);
}

// ---------------- final tiny MLP: 32 -> 16 -> 8 -> 2, one thread per graph -----
__global__ void mlp_kernel(const float* __restrict__ pooled,
                           const float* __restrict__ w2, const float* __restrict__ b2,
                           const float* __restrict__ w3, const float* __restrict__ b3,
                           const float* __restrict__ w4, const float* __restrict__ b4,
                           float* __restrict__ out)
{
    int g = blockIdx.x * 256 + threadIdx.x;
    if (g >= 512) return;
    float pbuf[32];
#pragma unroll
    for (int i = 0; i < 32; i++) pbuf[i] = pooled[g * 32 + i];
    float a[16];
#pragma unroll
    for (int j = 0; j < 16; j++) {
        float s = b2[j];
#pragma unroll
        for (int i = 0; i < 32; i++) s += w2[j * 32 + i] * pbuf[i];
        a[j] = lrelu(s);
    }
    float c8[8];
#pragma unroll
    for (int j = 0; j < 8; j++) {
        float s = b3[j];
#pragma unroll
        for (int i = 0; i < 16; i++) s += w3[j * 16 + i] * a[i];
        c8[j] = lrelu(s);
    }
#pragma unroll
    for (int j = 0; j < 2; j++) {
        float s = b4[j];
#pragma unroll
        for (int i = 0; i < 8; i++) s += w4[j * 8 + i] * c8[i];
        out[g * 2 + j] = lrelu(s);
    }
}

extern "C" void kernel_launch(void* const* d_in, const int* in_sizes, int n_in,
                              void* d_out, int out_size, void* d_ws, size_t ws_size,
                              hipStream_t stream)
{
    (void)in_sizes; (void)n_in; (void)out_size; (void)ws_size;
    const float* x      = (const float*)d_in[0];
    const int*   ei     = (const int*)d_in[1];
    const float* ew     = (const float*)d_in[2];
    const int*   batch  = (const int*)d_in[3];
    const float* W_ih1  = (const float*)d_in[4];
    const float* W_hh1  = (const float*)d_in[5];
    const float* b_ih1  = (const float*)d_in[6];
    const float* b_hh1  = (const float*)d_in[7];
    const float* W_ih2  = (const float*)d_in[8];
    const float* W_hh2  = (const float*)d_in[9];
    const float* b_ih2  = (const float*)d_in[10];
    const float* b_hh2  = (const float*)d_in[11];
    const float* fc1_w  = (const float*)d_in[12];
    const float* fc1_b  = (const float*)d_in[13];
    const float* gcn1_w = (const float*)d_in[14];
    const float* bn1_g  = (const float*)d_in[16];
    const float* bn1_b  = (const float*)d_in[17];
    const float* gcn2_w = (const float*)d_in[18];
    const float* bn2_g  = (const float*)d_in[20];
    const float* bn2_b  = (const float*)d_in[21];
    const float* fc2_w  = (const float*)d_in[22];
    const float* fc2_b  = (const float*)d_in[23];
    const float* fc3_w  = (const float*)d_in[24];
    const float* fc3_b  = (const float*)d_in[25];
    const float* fc4_w  = (const float*)d_in[26];
    const float* fc4_b  = (const float*)d_in[27];
    float* out = (float*)d_out;

    // -------- workspace layout (byte offsets) --------
    char* base = (char*)d_ws;
    const size_t MB = 1024 * 1024;
    float* gx1    = (float*)base;                       // 32MB: 4096*2048 f32
    u64*   h1pub  = (u64*)(base + 32 * MB);             // 16MB: 4096*512 u64
    u64*   h2pub  = (u64*)(base + 48 * MB);             //  8MB: 4096*256 u64
    float* h2seq  = (float*)(base + 56 * MB);           //  4MB: 4096*256 f32
    float* scale1 = (float*)(base + 60 * MB);           // 64
    float* shift1 = scale1 + 64;                        // 64
    float* scale2 = shift1 + 64;                        // 32
    float* shift2 = scale2 + 32;                        // 32
    // buffers used only AFTER lstm_pipe — aliased into gx1's space:
    float* h3     = (float*)base;                       // 4096*128
    float* m1     = h3 + (size_t)4096 * 128;            // 4096*64
    float* y1     = m1 + (size_t)4096 * 64;             // 4096*64 (bn in-place)
    float* m2     = y1 + (size_t)4096 * 64;             // 4096*32
    float* y2     = m2 + (size_t)4096 * 32;             // 4096*32 (bn in-place)
    float* pooled = y2 + (size_t)4096 * 32;             // 512*32

    dim3 b256(256);

    // fresh tags every launch (no cross-call state)
    hipMemsetAsync(h1pub, 0, (size_t)24 * MB, stream);  // h1pub + h2pub

    // gx1 = x @ W_ih1^T + (b_ih1 + b_hh1)   [4096,2048]
    gemm_bias<false><<<dim3(2048 / 64, 4096 / 64), b256, 0, stream>>>(
        x, W_ih1, b_ih1, b_hh1, gx1, 4096, 2048, 1280);

    // both LSTM scans, pipelined (persistent, 96 WGs)
    lstm_pipe<<<96, b256, 0, stream>>>(gx1, W_hh1, W_ih2, W_hh2, b_ih2, b_hh2,
                                       h1pub, h2pub, h2seq);

    // fc1 + lrelu  [4096,128]
    gemm_bias<true><<<dim3(128 / 64, 4096 / 64), b256, 0, stream>>>(
        h2seq, fc1_w, fc1_b, nullptr, h3, 4096, 128, 256);

    // gcn1 linear [4096,64]  (bias cancels in BN)
    gemm_bias<false><<<dim3(1, 4096 / 64), b256, 0, stream>>>(
        h3, gcn1_w, nullptr, nullptr, m1, 4096, 64, 128);
    hipMemsetAsync(y1, 0, (size_t)4096 * 64 * sizeof(float), stream);
    gcn_scatter<<<(32768 * 64) / 256, b256, 0, stream>>>(m1, ei, ew, y1, 6, 32768);
    bn_stats<<<64, b256, 0, stream>>>(y1, bn1_g, bn1_b, scale1, shift1, 4096, 64);
    bn_apply<<<(4096 * 64) / 256, b256, 0, stream>>>(y1, scale1, shift1, y1, 63, 4096 * 64);

    // gcn2 linear [4096,32]
    gemm_bias<false><<<dim3(1, 4096 / 64), b256, 0, stream>>>(
        y1, gcn2_w, nullptr, nullptr, m2, 4096, 32, 64);
    hipMemsetAsync(y2, 0, (size_t)4096 * 32 * sizeof(float), stream);
    gcn_scatter<<<(32768 * 32) / 256, b256, 0, stream>>>(m2, ei, ew, y2, 5, 32768);
    bn_stats<<<32, b256, 0, stream>>>(y2, bn2_g, bn2_b, scale2, shift2, 4096, 32);
    bn_apply<<<(4096 * 32) / 256, b256, 0, stream>>>(y2, scale2, shift2, y2, 31, 4096 * 32);

    // pool + MLP head
    hipMemsetAsync(pooled, 0, (size_t)512 * 32 * sizeof(float), stream);
    pool_kernel<<<(4096 * 32) / 256, b256, 0, stream>>>(y2, batch, pooled, 4096 * 32);
    mlp_kernel<<<2, b256, 0, stream>>>(pooled, fc2_w, fc2_b, fc3_w, fc3_b,
                                       fc4_w, fc4_b, out);
}